// Round 6
// baseline (11736.464 us; speedup 1.0000x reference)
//
#include <hip/hip_runtime.h>
#include <hip/hip_bf16.h>
#include <cstdint>
#include <cstddef>

#define BB 64
#define TT 512
#define DD 256
#define HH 512
#define G4 2048   // 4*H

typedef __bf16 bf16x8 __attribute__((ext_vector_type(8)));
typedef __bf16 bf16x4 __attribute__((ext_vector_type(4)));
typedef float  f32x4  __attribute__((ext_vector_type(4)));
typedef unsigned long long ull_t;

// bits[15:14] of every bf16 h element are the step tag:
//   01 / 10 = alternating step tags (1 + ((step>>1)&1))
//   11 = init sentinel (memset 0xFF)
//   (valid h in (0,1) has bits[15:14] == 00 before tagging)
#define TAGM 0xC000C000C000C000ULL

// Safety: bounded spin. ~4ms >> any legitimate wait; on overflow the wave
// proceeds (test fails visibly instead of hanging the container).
#define SPIN_CAP (1 << 16)

__device__ __forceinline__ float sigf(float x) {
  return 1.0f / (1.0f + __expf(-x));
}

// Agent-coherent load: bypasses the non-coherent L1/L2, reads the coherence point.
__device__ __forceinline__ ull_t coh_load_u64(const __bf16* p) {
  return __hip_atomic_load(reinterpret_cast<const ull_t*>(p),
                           __ATOMIC_RELAXED, __HIP_MEMORY_SCOPE_AGENT);
}
// Agent-scope atomic swap: executes AT the coherence point => immediate
// global visibility of the published h pair.
__device__ __forceinline__ void coh_pub_u32(unsigned* p, unsigned v) {
  (void)__hip_atomic_exchange(p, v, __ATOMIC_RELAXED, __HIP_MEMORY_SCOPE_AGENT);
}

// Convert x fp32 [B][T][D] -> bf16 (same layout) in ws.
__global__ void cvt_x_kernel(const float* __restrict__ x, __bf16* __restrict__ xb) {
  int i = (blockIdx.x * 256 + threadIdx.x) * 4;
  float4 v = *(const float4*)(x + i);
  bf16x4 o;
  o[0] = (__bf16)v.x; o[1] = (__bf16)v.y; o[2] = (__bf16)v.z; o[3] = (__bf16)v.w;
  *(bf16x4*)(xb + i) = o;
}

// Persistent bidirectional LSTM, tag-in-data sync, GATE-PACKED N.
// Grid: 256 blocks x 256 threads, 1 block/CU. dir = blockIdx>>7, s = blockIdx&127
// owns hidden units [4s, 4s+4). The MFMA N=16 packs 4 gates x 4 units:
// B-frag col j -> (gate j>>2, unit j&3). A wave therefore needs only ONE
// B-fragment per K-tile: 24 frags = 96 VGPRs -- small enough that the
// allocator keeps them RESIDENT (rounds 0-5 all spilled/resank their 48-96
// fragment arrays; that per-step scratch/L2 re-read was the real ~5us/step
// bottleneck masquerading as sync latency).
// Wave (tid>>6) = M-tile of 16 batch rows; waves fully independent, no LDS,
// no barriers. Sister lanes (j, j^4, j^8, j^12) exchange gate values via two
// shfl_xor rounds; all lanes compute identical gates, gt==0 lanes store+publish.
__launch_bounds__(256, 1)
__global__ void lstm_kernel(const __bf16* __restrict__ xb,
                            const float* __restrict__ Wf, const float* __restrict__ Uf,
                            const float* __restrict__ bf_,
                            const float* __restrict__ Wb, const float* __restrict__ Ub,
                            const float* __restrict__ bb_,
                            __bf16* __restrict__ hbuf,          // [2 dir][2 phase][64][512]
                            float* __restrict__ out,            // d_out
                            __bf16* __restrict__ hsb) {         // [T][B][H] bwd halves
  const int bx  = blockIdx.x;
  const int dir = bx >> 7;
  const int s   = bx & 127;
  const float* Wd = dir ? Wb : Wf;
  const float* Ud = dir ? Ub : Uf;
  const float* bd = dir ? bb_ : bf_;
  __bf16* hb = hbuf + (size_t)dir * 2 * BB * HH;

  const int tid  = threadIdx.x;
  const int mt   = tid >> 6;       // wave id = M-tile (16 batch rows)
  const int lane = tid & 63;
  const int j    = lane & 15;      // B col = (gate, unit)
  const int q    = lane >> 4;      // quad
  const int gt   = j >> 2;         // gate (Keras order i,f,g,o)
  const int u    = j & 3;          // unit within block
  const int colg = s * 4 + u;      // hidden unit index

  // ---- gather weight B-fragments (one-time): 24 frags = 96 VGPR, resident
  bf16x8 wfrag[24];
#pragma unroll
  for (int kt = 0; kt < 24; ++kt) {
    const int col = gt * HH + colg;
    bf16x8 v;
#pragma unroll
    for (int e = 0; e < 8; ++e) {
      const int k = kt * 32 + q * 8 + e;
      const float w = (k < DD) ? Wd[(size_t)k * G4 + col]
                               : Ud[(size_t)(k - DD) * G4 + col];
      v[e] = (__bf16)w;
    }
    wfrag[kt] = v;
  }
  const float bg = bd[gt * HH + colg];

  float cst[4] = {0.f, 0.f, 0.f, 0.f};   // cell state for (rows mt*16+q*4+r, unit u)
  const size_t outTail = (size_t)BB * TT * HH;

  for (int tau = 0; tau < TT; ++tau) {
    const int t = dir ? (TT - 1 - tau) : tau;
    const __bf16* hrow = hb + (size_t)(tau & 1) * (BB * HH)
                            + (size_t)(mt * 16 + j) * HH + q * 8;
    const ull_t epat = (ull_t)(1u + ((unsigned)(tau >> 1) & 1u)) * 0x4000400040004000ULL;

    // issue ALL h gather loads first (speculative; tag verify below catches
    // not-yet-published data) so the MALL round-trip hides under the x MFMAs
    ull_t hld[32];
    if (tau) {
#pragma unroll
      for (int kt = 0; kt < 16; ++kt) {
        hld[2*kt]   = coh_load_u64(hrow + kt * 32);
        hld[2*kt+1] = coh_load_u64(hrow + kt * 32 + 4);
      }
    }

    // x-part (kt 0..7, no h dependency), single packed accumulator
    const __bf16* xrow = xb + ((size_t)(mt * 16 + j) * TT + t) * DD + q * 8;
    f32x4 acc = (f32x4){bg, bg, bg, bg};
#pragma unroll
    for (int kt = 0; kt < 8; ++kt) {
      bf16x8 a = *(const bf16x8*)(xrow + kt * 32);
      acc = __builtin_amdgcn_mfma_f32_16x16x32_bf16(a, wfrag[kt], acc, 0, 0, 0);
    }

    // h-part: verify tags per batch of 4 K-tiles (capped retry), then MFMA
    if (tau) {
#pragma unroll
      for (int kb = 0; kb < 4; ++kb) {
        int guard = 0;
        for (;;) {
          int ok = 1;
#pragma unroll
          for (int i = 0; i < 8; ++i) ok &= ((hld[kb * 8 + i] & TAGM) == epat);
          if (__all(ok)) break;
          if (++guard > SPIN_CAP) break;   // fail visibly, never hang
          __builtin_amdgcn_s_sleep(1);
#pragma unroll
          for (int i = 0; i < 4; ++i) {
            hld[kb*8 + 2*i]   = coh_load_u64(hrow + (kb * 4 + i) * 32);
            hld[kb*8 + 2*i+1] = coh_load_u64(hrow + (kb * 4 + i) * 32 + 4);
          }
        }
#pragma unroll
        for (int i = 0; i < 4; ++i) {
          union { ull_t uq[2]; bf16x8 v; } uu;
          uu.uq[0] = hld[kb*8 + 2*i]   & ~TAGM;
          uu.uq[1] = hld[kb*8 + 2*i+1] & ~TAGM;
          acc = __builtin_amdgcn_mfma_f32_16x16x32_bf16(uu.v, wfrag[8 + kb * 4 + i], acc, 0, 0, 0);
        }
      }
    }

    // gate exchange among sister lanes (j, j^4, j^8, j^12):
    //   va holds gate gt, vb gate gt^1, vc gate gt^2, vd gate gt^3 (same rows, same unit)
    f32x4 vb, vc, vd;
#pragma unroll
    for (int e = 0; e < 4; ++e) {
      vb[e] = __shfl_xor(acc[e], 4);
      vc[e] = __shfl_xor(acc[e], 8);
      vd[e] = __shfl_xor(vb[e], 8);
    }
    const bool p  = (gt & 1) != 0;
    const bool h2 = (gt & 2) != 0;

    const unsigned ptag = ((1u + ((unsigned)((tau + 1) >> 1) & 1u)) << 14);
    __bf16* hnext = hb + (size_t)((tau + 1) & 1) * (BB * HH);
    unsigned myv[4];
#pragma unroll
    for (int r = 0; r < 4; ++r) {
      // sel(k) = {va,vb,vc,vd}[k];  z_G = sel(gt ^ G)
      const float i1 = p ? vb[r] : acc[r];   // sel(gt)      inner
      const float i2 = p ? vd[r] : vc[r];
      const float iA = p ? acc[r] : vb[r];   // sel(gt^1)    inner
      const float iB = p ? vc[r] : vd[r];
      const float zi = h2 ? i2 : i1;         // gate i
      const float zf = h2 ? iB : iA;         // gate f
      const float zg = h2 ? i1 : i2;         // gate g
      const float zo = h2 ? iA : iB;         // gate o
      const float gi = sigf(zi), gf = sigf(zf), gg = sigf(zg), go = sigf(zo);
      const float cn = gf * cst[r] + gi * gg;
      cst[r] = cn;
      const float hn = go * sigf(cn);
      union { __bf16 b; unsigned short us; } cv;
      cv.b = (__bf16)hn;                     // hn in (0,1) => bits[15:14] == 00
      myv[r] = (unsigned)cv.us | ptag;
      if (gt == 0) {                         // one lane per (row, unit) stores
        const int orow = mt * 16 + q * 4 + r;
        if (dir == 0) {
          out[(size_t)orow * (TT * HH) + (size_t)t * HH + colg] = 0.5f * hn;
        } else {
          hsb[(size_t)t * (BB * HH) + (size_t)orow * HH + colg] = (__bf16)hn;
        }
        if (tau == TT - 1) {
          float* base = out + outTail + (size_t)dir * (2 * BB * HH);
          base[(size_t)orow * HH + colg] = hn;                 // hF / hB
          base[(size_t)BB * HH + (size_t)orow * HH + colg] = cn; // cF / cB
        }
      }
    }

    // publish h_{tau+1}: pair adjacent units, lanes j in {0,2} issue 4B agent atomics
    unsigned pr[4];
#pragma unroll
    for (int r = 0; r < 4; ++r) pr[r] = __shfl_xor((int)myv[r], 1);
    if (gt == 0 && (u & 1) == 0) {
#pragma unroll
      for (int r = 0; r < 4; ++r) {
        const int orow = mt * 16 + q * 4 + r;
        unsigned pk = (myv[r] & 0xFFFFu) | (pr[r] << 16);
        coh_pub_u32((unsigned*)&hnext[(size_t)orow * HH + colg], pk);
      }
    }
  }
}

// out[b,t,c] += 0.5 * hsb[t,b,c]
__global__ void combine_kernel(float* __restrict__ out, const __bf16* __restrict__ hsb) {
  const size_t i = ((size_t)blockIdx.x * 256 + threadIdx.x) * 4;
  const size_t b = i >> 18;
  const size_t t = (i >> 9) & 511;
  const size_t c = i & 511;
  bf16x4 hv = *(const bf16x4*)(hsb + t * (BB * HH) + b * HH + c);
  float4 v = *(float4*)(out + i);
  v.x += 0.5f * (float)hv[0];
  v.y += 0.5f * (float)hv[1];
  v.z += 0.5f * (float)hv[2];
  v.w += 0.5f * (float)hv[3];
  *(float4*)(out + i) = v;
}

extern "C" void kernel_launch(void* const* d_in, const int* in_sizes, int n_in,
                              void* d_out, int out_size, void* d_ws, size_t ws_size,
                              hipStream_t stream) {
  (void)in_sizes; (void)n_in; (void)out_size; (void)ws_size;
  const float* x   = (const float*)d_in[0];
  // d_in[1] = 'hidden' is unused by the reference (h0 = c0 = 0)
  const float* Wf  = (const float*)d_in[2];
  const float* Uf  = (const float*)d_in[3];
  const float* bf_ = (const float*)d_in[4];
  const float* Wb  = (const float*)d_in[5];
  const float* Ub  = (const float*)d_in[6];
  const float* bb_ = (const float*)d_in[7];
  float* out = (float*)d_out;
  char* ws = (char*)d_ws;

  // ws layout:
  //   [1024, 263168)  : hbuf  2 dir x 2 phase x 64 x 512 bf16 (0xFF = init sentinel)
  //   [512K, 16.5M)   : x bf16 [B][T][D]
  //   [16.5M, 48.5M)  : hsb bf16 [T][B][H]
  __bf16* hbuf = (__bf16*)(ws + 1024);
  __bf16* xb   = (__bf16*)(ws + (1 << 19));
  __bf16* hsb  = (__bf16*)(ws + (1 << 19) + (size_t)BB * TT * DD * 2);

  hipMemsetAsync(ws, 0xFF, 1 << 19, stream);  // tag 11 = "never written" sentinel
  cvt_x_kernel<<<dim3((BB * TT * DD) / 1024), dim3(256), 0, stream>>>(x, xb);
  lstm_kernel<<<dim3(256), dim3(256), 0, stream>>>(xb, Wf, Uf, bf_, Wb, Ub, bb_,
                                                   hbuf, out, hsb);
  combine_kernel<<<dim3((BB * TT * HH) / 1024), dim3(256), 0, stream>>>(out, hsb);
}

// Round 7
// 5625.158 us; speedup vs baseline: 2.0864x; 2.0864x over previous
//
#include <hip/hip_runtime.h>
#include <hip/hip_bf16.h>
#include <cstdint>
#include <cstddef>

#define BB 64
#define TT 512
#define DD 256
#define HH 512
#define G4 2048   // 4*H

typedef __bf16 bf16x8 __attribute__((ext_vector_type(8)));
typedef __bf16 bf16x4 __attribute__((ext_vector_type(4)));
typedef float  f32x4  __attribute__((ext_vector_type(4)));
typedef unsigned long long ull_t;

// bits[15:14] of every bf16 h element are the step tag:
//   01 / 10 = alternating step tags (1 + ((step>>1)&1))
//   11 = init sentinel (memset 0xFF)
//   (valid h in (0,1) has bits[15:14] == 00 before tagging)
#define TAGM 0xC000C000C000C000ULL

// Safety: bounded spin. ~4ms >> any legitimate wait; on overflow the wave
// proceeds (test fails visibly instead of hanging the container).
#define SPIN_CAP (1 << 16)

__device__ __forceinline__ float sigf(float x) {
  return 1.0f / (1.0f + __expf(-x));
}

// Agent-coherent load: bypasses the non-coherent L1/L2, reads the coherence point.
__device__ __forceinline__ ull_t coh_load_u64(const __bf16* p) {
  return __hip_atomic_load(reinterpret_cast<const ull_t*>(p),
                           __ATOMIC_RELAXED, __HIP_MEMORY_SCOPE_AGENT);
}
// Agent-scope atomic swap: executes AT the coherence point => immediate
// global visibility of the published h pair.
__device__ __forceinline__ void coh_pub_u32(unsigned* p, unsigned v) {
  (void)__hip_atomic_exchange(p, v, __ATOMIC_RELAXED, __HIP_MEMORY_SCOPE_AGENT);
}

// Convert x fp32 [B][T][D] -> bf16 (same layout) in ws.
__global__ void cvt_x_kernel(const float* __restrict__ x, __bf16* __restrict__ xb) {
  int i = (blockIdx.x * 256 + threadIdx.x) * 4;
  float4 v = *(const float4*)(x + i);
  bf16x4 o;
  o[0] = (__bf16)v.x; o[1] = (__bf16)v.y; o[2] = (__bf16)v.z; o[3] = (__bf16)v.w;
  *(bf16x4*)(xb + i) = o;
}

// Persistent bidirectional LSTM, tag-in-data sync, WEIGHTS IN LDS.
// Grid: 64 blocks x 256 threads (R1/R4 geometry: dir = blockIdx>>5, s =
// blockIdx&31 owns hidden units [16s,16s+16); wave (tid>>6) = M-tile of 16
// batch rows; waves fully independent, no per-step barriers).
//
// Round 0-5 lesson: this block shape needs 96 B-fragments (768 K x 64 cols),
// and holding them in VGPRs means 384 regs/wave -> the allocator spills
// ~half and the per-step scratch re-read (~5us) was the real bottleneck.
// Round 6 lesson: shrinking the N-slice to de-spill quadruples gather traffic.
// Fix: the 96KB weight slice lives in LDS ONCE per block (shared by all 4
// waves, read-only after a one-time init; frag layout [g*24+kt][lane] is
// wave-agnostic and conflict-free for ds_read_b128). Per-step LDS stream =
// 4 waves x 96KB = 384KB/CU ~ 1.25us, pipelined under MFMA + gather wait.
// Registers drop to ~150 -> no spill, gather traffic unchanged vs R1.
__launch_bounds__(256, 1)
__global__ void lstm_kernel(const __bf16* __restrict__ xb,
                            const float* __restrict__ Wf, const float* __restrict__ Uf,
                            const float* __restrict__ bf_,
                            const float* __restrict__ Wb, const float* __restrict__ Ub,
                            const float* __restrict__ bb_,
                            __bf16* __restrict__ hbuf,          // [2 dir][2 phase][64][512]
                            float* __restrict__ out,            // d_out
                            __bf16* __restrict__ hsb) {         // [T][B][H] bwd halves
  const int bx  = blockIdx.x;
  const int dir = bx >> 5;
  const int s   = bx & 31;
  const float* Wd = dir ? Wb : Wf;
  const float* Ud = dir ? Ub : Uf;
  const float* bd = dir ? bb_ : bf_;
  __bf16* hb = hbuf + (size_t)dir * 2 * BB * HH;

  const int tid  = threadIdx.x;
  const int mt   = tid >> 6;      // wave id = M-tile (16 batch rows)
  const int lane = tid & 63;
  const int j    = lane & 15;     // A row offset / B col / D col
  const int q    = lane >> 4;     // quad
  const int colg = s * 16 + j;    // hidden unit index this lane owns

  // Weight B-fragments, one copy per block: frag f = g*24+kt, per-lane 16B.
  // 96 frags x 64 lanes x 16B = 96 KiB.
  __shared__ bf16x8 wlds[96][64];

  // ---- one-time cooperative init: wave w loads gate w's 24 K-tiles ----
  {
    const int g   = mt;                       // gate this wave fills
    const int col = g * HH + colg;
#pragma unroll
    for (int kt = 0; kt < 24; ++kt) {
      bf16x8 v;
#pragma unroll
      for (int e = 0; e < 8; ++e) {
        const int k = kt * 32 + q * 8 + e;
        const float w = (k < DD) ? Wd[(size_t)k * G4 + col]
                                 : Ud[(size_t)(k - DD) * G4 + col];
        v[e] = (__bf16)w;
      }
      wlds[g * 24 + kt][lane] = v;
    }
  }
  __syncthreads();   // only barrier in the kernel; LDS is read-only after this

  float bg[4];
#pragma unroll
  for (int g = 0; g < 4; ++g) bg[g] = bd[g * HH + colg];

  float cst[4] = {0.f, 0.f, 0.f, 0.f};   // cell state, rows mt*16+q*4+r
  const size_t outTail = (size_t)BB * TT * HH;

  for (int tau = 0; tau < TT; ++tau) {
    const int t = dir ? (TT - 1 - tau) : tau;
    const __bf16* hrow = hb + (size_t)(tau & 1) * (BB * HH)
                            + (size_t)(mt * 16 + j) * HH + q * 8;
    const ull_t epat = (ull_t)(1u + ((unsigned)(tau >> 1) & 1u)) * 0x4000400040004000ULL;

    // issue ALL h gather loads first (speculative; tag verify below catches
    // not-yet-published data) so the MALL round-trip hides under the x MFMAs
    ull_t hld[32];
    if (tau) {
#pragma unroll
      for (int kt = 0; kt < 16; ++kt) {
        hld[2*kt]   = coh_load_u64(hrow + kt * 32);
        hld[2*kt+1] = coh_load_u64(hrow + kt * 32 + 4);
      }
    }

    // x-part (kt 0..7, no h dependency); B-frags streamed from LDS
    const __bf16* xrow = xb + ((size_t)(mt * 16 + j) * TT + t) * DD + q * 8;
    f32x4 acc[4];
#pragma unroll
    for (int g = 0; g < 4; ++g) acc[g] = (f32x4){bg[g], bg[g], bg[g], bg[g]};
#pragma unroll
    for (int kt = 0; kt < 8; ++kt) {
      bf16x8 a = *(const bf16x8*)(xrow + kt * 32);
#pragma unroll
      for (int g = 0; g < 4; ++g) {
        bf16x8 b = wlds[g * 24 + kt][lane];
        acc[g] = __builtin_amdgcn_mfma_f32_16x16x32_bf16(a, b, acc[g], 0, 0, 0);
      }
    }

    // h-part: verify tags per batch of 4 K-tiles (capped retry), then MFMA
    if (tau) {
#pragma unroll
      for (int kb = 0; kb < 4; ++kb) {
        int guard = 0;
        for (;;) {
          int ok = 1;
#pragma unroll
          for (int i = 0; i < 8; ++i) ok &= ((hld[kb * 8 + i] & TAGM) == epat);
          if (__all(ok)) break;
          if (++guard > SPIN_CAP) break;   // fail visibly, never hang
          __builtin_amdgcn_s_sleep(1);
#pragma unroll
          for (int i = 0; i < 4; ++i) {
            hld[kb*8 + 2*i]   = coh_load_u64(hrow + (kb * 4 + i) * 32);
            hld[kb*8 + 2*i+1] = coh_load_u64(hrow + (kb * 4 + i) * 32 + 4);
          }
        }
#pragma unroll
        for (int i = 0; i < 4; ++i) {
          union { ull_t uq[2]; bf16x8 v; } uu;
          uu.uq[0] = hld[kb*8 + 2*i]   & ~TAGM;
          uu.uq[1] = hld[kb*8 + 2*i+1] & ~TAGM;
          const int kt = 8 + kb * 4 + i;
#pragma unroll
          for (int g = 0; g < 4; ++g) {
            bf16x8 b = wlds[g * 24 + kt][lane];
            acc[g] = __builtin_amdgcn_mfma_f32_16x16x32_bf16(uu.v, b, acc[g], 0, 0, 0);
          }
        }
      }
    }

    // gates + state update (all-sigmoid variant per reference)
    const unsigned ptag = ((1u + ((unsigned)((tau + 1) >> 1) & 1u)) << 14);
    __bf16* hnext = hb + (size_t)((tau + 1) & 1) * (BB * HH);
    unsigned myv[4];
#pragma unroll
    for (int r = 0; r < 4; ++r) {
      const float zi = acc[0][r], zf = acc[1][r], zg = acc[2][r], zo = acc[3][r];
      const float gi = sigf(zi), gf = sigf(zf), gg = sigf(zg), go = sigf(zo);
      const float cn = gf * cst[r] + gi * gg;
      cst[r] = cn;
      const float hn = go * sigf(cn);
      union { __bf16 b; unsigned short us; } cv;
      cv.b = (__bf16)hn;                         // hn in (0,1) => bits[15:14] == 00
      myv[r] = (unsigned)cv.us | ptag;
      const int orow = mt * 16 + q * 4 + r;      // batch row
      if (dir == 0) {
        out[(size_t)orow * (TT * HH) + (size_t)t * HH + colg] = 0.5f * hn;
      } else {
        hsb[(size_t)t * (BB * HH) + (size_t)orow * HH + colg] = (__bf16)hn;
      }
      if (tau == TT - 1) {
        float* base = out + outTail + (size_t)dir * (2 * BB * HH);
        base[(size_t)orow * HH + colg] = hn;                 // hF / hB
        base[(size_t)BB * HH + (size_t)orow * HH + colg] = cn; // cF / cB
      }
    }

    // publish h_{tau+1}: pair adjacent cols, even lanes issue 4B agent atomics
    unsigned pr[4];
#pragma unroll
    for (int r = 0; r < 4; ++r) pr[r] = __shfl_xor((int)myv[r], 1);
    if ((lane & 1) == 0) {
#pragma unroll
      for (int r = 0; r < 4; ++r) {
        const int orow = mt * 16 + q * 4 + r;
        unsigned pk = (myv[r] & 0xFFFFu) | (pr[r] << 16);
        coh_pub_u32((unsigned*)&hnext[(size_t)orow * HH + colg], pk);
      }
    }
  }
}

// out[b,t,c] += 0.5 * hsb[t,b,c]
__global__ void combine_kernel(float* __restrict__ out, const __bf16* __restrict__ hsb) {
  const size_t i = ((size_t)blockIdx.x * 256 + threadIdx.x) * 4;
  const size_t b = i >> 18;
  const size_t t = (i >> 9) & 511;
  const size_t c = i & 511;
  bf16x4 hv = *(const bf16x4*)(hsb + t * (BB * HH) + b * HH + c);
  float4 v = *(float4*)(out + i);
  v.x += 0.5f * (float)hv[0];
  v.y += 0.5f * (float)hv[1];
  v.z += 0.5f * (float)hv[2];
  v.w += 0.5f * (float)hv[3];
  *(float4*)(out + i) = v;
}

extern "C" void kernel_launch(void* const* d_in, const int* in_sizes, int n_in,
                              void* d_out, int out_size, void* d_ws, size_t ws_size,
                              hipStream_t stream) {
  (void)in_sizes; (void)n_in; (void)out_size; (void)ws_size;
  const float* x   = (const float*)d_in[0];
  // d_in[1] = 'hidden' is unused by the reference (h0 = c0 = 0)
  const float* Wf  = (const float*)d_in[2];
  const float* Uf  = (const float*)d_in[3];
  const float* bf_ = (const float*)d_in[4];
  const float* Wb  = (const float*)d_in[5];
  const float* Ub  = (const float*)d_in[6];
  const float* bb_ = (const float*)d_in[7];
  float* out = (float*)d_out;
  char* ws = (char*)d_ws;

  // ws layout:
  //   [1024, 263168)  : hbuf  2 dir x 2 phase x 64 x 512 bf16 (0xFF = init sentinel)
  //   [512K, 16.5M)   : x bf16 [B][T][D]
  //   [16.5M, 48.5M)  : hsb bf16 [T][B][H]
  __bf16* hbuf = (__bf16*)(ws + 1024);
  __bf16* xb   = (__bf16*)(ws + (1 << 19));
  __bf16* hsb  = (__bf16*)(ws + (1 << 19) + (size_t)BB * TT * DD * 2);

  hipMemsetAsync(ws, 0xFF, 1 << 19, stream);  // tag 11 = "never written" sentinel
  cvt_x_kernel<<<dim3((BB * TT * DD) / 1024), dim3(256), 0, stream>>>(x, xb);
  lstm_kernel<<<dim3(64), dim3(256), 0, stream>>>(xb, Wf, Uf, bf_, Wb, Ub, bb_,
                                                  hbuf, out, hsb);
  combine_kernel<<<dim3((BB * TT * HH) / 1024), dim3(256), 0, stream>>>(out, hsb);
}